// Round 5
// baseline (430.051 us; speedup 1.0000x reference)
//
#include <hip/hip_runtime.h>
#include <hip/hip_bf16.h>
#include <cstdint>
#include <cstddef>

#define K_DIM 4096

typedef __bf16 bf16x8 __attribute__((ext_vector_type(8)));
typedef float  f32x4  __attribute__((ext_vector_type(4)));
typedef unsigned short ushort8 __attribute__((ext_vector_type(8)));

struct KronPtrs { const float* a[8]; const float* b[8]; };

// ---------------------------------------------------------------------------
// Fused prologue (unchanged from R2 — write-bound, ~20 µs).
// ---------------------------------------------------------------------------
__global__ __launch_bounds__(256) void prologue_kernel(
        KronPtrs P,
        const float* __restrict__ x,
        __hip_bfloat16* __restrict__ Wb,
        __hip_bfloat16* __restrict__ Xb)
{
    __shared__ __align__(16) float sa[1080];
    __shared__ __align__(16) float sb[1080];

    const int tid = threadIdx.x;

    if (blockIdx.x < 8192) {
        const size_t t = (size_t)blockIdx.x * 256 + tid;
        const size_t o = t * 8;
        const float4 v0 = *(const float4*)(x + o);
        const float4 v1 = *(const float4*)(x + o + 4);
        union { __hip_bfloat16 h[8]; ushort8 v; } u;
        u.h[0] = __float2bfloat16(v0.x);
        u.h[1] = __float2bfloat16(v0.y);
        u.h[2] = __float2bfloat16(v0.z);
        u.h[3] = __float2bfloat16(v0.w);
        u.h[4] = __float2bfloat16(v1.x);
        u.h[5] = __float2bfloat16(v1.y);
        u.h[6] = __float2bfloat16(v1.z);
        u.h[7] = __float2bfloat16(v1.w);
        *(ushort8*)(void*)(Xb + o) = u.v;
        return;
    }

    const int row = blockIdx.x - 8192;

#define STAGE(IDX, MA, LB, OA, OB)                                             \
    {                                                                          \
        const int mb_ = 1 << (LB);                                             \
        const float* ap = P.a[IDX] + (size_t)(row >> (LB)) * (MA);             \
        const float* bp = P.b[IDX] + (size_t)(row & (mb_ - 1)) * mb_;          \
        for (int i = tid; i < (MA); i += 256) sa[(OA) + i] = ap[i];            \
        for (int i = tid; i < mb_;  i += 256) sb[(OB) + i] = bp[i];            \
    }

    STAGE(0,  64, 6,   0,    0)
    STAGE(1,  64, 6,  64,   64)
    STAGE(2,  32, 7, 128,  128)
    STAGE(3, 128, 5, 160,  256)
    STAGE(4,  16, 8, 288,  288)
    STAGE(5, 256, 4, 304,  544)
    STAGE(6,   8, 9, 560,  560)
    STAGE(7, 512, 3, 568, 1072)
#undef STAGE

    __syncthreads();

    const float s = 0.17677669529663687f;  // 1 / (2*sqrt(8))
    const int q0 = tid << 4;

#pragma unroll
    for (int g = 0; g < 2; ++g) {
        const int q8 = q0 + (g << 3);
        float acc[8] = {0.f,0.f,0.f,0.f,0.f,0.f,0.f,0.f};

#define KTERM(LB, OA, OB)                                                      \
    {                                                                          \
        const int mb_   = 1 << (LB);                                           \
        const float av  = sa[(OA) + (q8 >> (LB))];                             \
        const float* bp = sb + (OB) + (q8 & (mb_ - 1));                        \
        const float4 x0 = *(const float4*)(bp);                                \
        const float4 x1 = *(const float4*)(bp + 4);                            \
        acc[0] += av * x0.x; acc[1] += av * x0.y;                              \
        acc[2] += av * x0.z; acc[3] += av * x0.w;                              \
        acc[4] += av * x1.x; acc[5] += av * x1.y;                              \
        acc[6] += av * x1.z; acc[7] += av * x1.w;                              \
    }

        KTERM(6,   0,    0)
        KTERM(6,  64,   64)
        KTERM(7, 128,  128)
        KTERM(5, 160,  256)
        KTERM(8, 288,  288)
        KTERM(4, 304,  544)
        KTERM(9, 560,  560)
        KTERM(3, 568, 1072)
#undef KTERM

        union { __hip_bfloat16 h[8]; ushort8 v; } u;
#pragma unroll
        for (int i = 0; i < 8; ++i) u.h[i] = __float2bfloat16(acc[i] * s);
        *(ushort8*)(void*)(Wb + (size_t)row * K_DIM + q8) = u.v;
    }
}

// ---------------------------------------------------------------------------
// GEMM: C[m][n] = sum_k Wb[m][k] * Xb[n][k] + bias[n]   (C = W @ X^T)
// R5: A (W) staged in LDS via global_load_lds (R4's verified conflict-free
// 16x16 pattern); B (X) fragments loaded DIRECTLY global->VGPR — the
// 16x16x32 B-fragment is 16 contiguous bytes of an Xb row, so one
// global_load_dwordx4 per frag.  B loads are issued BEFORE __syncthreads so
// their latency hides under the A-DMA barrier drain we already pay; the
// MFMA loop then waits only on A ds_reads.  LDS pipe traffic halves
// (no lsB writes, no B ds_reads).
// ---------------------------------------------------------------------------
__device__ __forceinline__ void gload_lds16(const void* g, void* l)
{
    __builtin_amdgcn_global_load_lds((const __attribute__((address_space(1))) void*)g,
                                     (__attribute__((address_space(3))) void*)l,
                                     16, 0, 0);
}

__global__ __launch_bounds__(256) void gemm_kernel(
        const __hip_bfloat16* __restrict__ Wb,
        const __hip_bfloat16* __restrict__ Xb,
        const float* __restrict__ bias,
        float* __restrict__ C)
{
    __shared__ __align__(16) __hip_bfloat16 lsA[128 * 64];

    const int tid  = threadIdx.x;
    const int lane = tid & 63;
    const int wid  = tid >> 6;
    const int wr   = wid >> 1;   // wave row 0..1
    const int wc   = wid & 1;    // wave col 0..1

    const int bm = blockIdx.y << 7;
    const int bn = blockIdx.x << 7;

    // A staging swizzle: within a 1KB chunk (8 rows x 128B), physical
    // 16B-chunk p of row r holds LOGICAL chunk p ^ (r&7); lane L writes
    // (row L>>3, phys chunk L&7) -> fetches logical chunk (L&7)^(L>>3).
    const int sr = lane >> 3;
    const int lc = (lane & 7) ^ sr;

    const __hip_bfloat16* gA[4];
#pragma unroll
    for (int i = 0; i < 4; ++i) {
        const int c = (wid << 2) + i;             // 8-row chunk 0..15
        gA[i] = Wb + (size_t)(bm + c * 8 + sr) * K_DIM + lc * 8;
    }

    const int fr = lane & 15;   // fragment row within 16x16 tile
    const int fq = lane >> 4;   // quad 0..3 (selects 8-elem k-chunk)
    const int fx = lane & 7;    // read-side swizzle xor (= frag row & 7)

    // B direct-load pointers: lane reads Xb[bn + (wc<<6) + ni*16 + fr]
    // [k = k0 + kk*32 + fq*8 .. +7]  — 16B contiguous.
    const __hip_bfloat16* gB[4];
#pragma unroll
    for (int ni = 0; ni < 4; ++ni)
        gB[ni] = Xb + (size_t)(bn + (wc << 6) + (ni << 4) + fr) * K_DIM + fq * 8;

    f32x4 acc[4][4];
#pragma unroll
    for (int i = 0; i < 4; ++i)
#pragma unroll
        for (int j = 0; j < 4; ++j) acc[i][j] = (f32x4)(0.0f);

    // k0-invariant LDS read base for A.
    const __hip_bfloat16* aRd = lsA + ((wr << 6) + fr) * 64;

    for (int k0 = 0; k0 < K_DIM; k0 += 64) {
        // A tile -> LDS (async DMA)
#pragma unroll
        for (int i = 0; i < 4; ++i) {
            const int c = (wid << 2) + i;
            gload_lds16(gA[i], lsA + c * 512);
            gA[i] += 64;
        }
        // B frags -> VGPR, in flight concurrently with the A DMA;
        // drained by the same pre-barrier vmcnt(0).
        bf16x8 bfv[2][4];
#pragma unroll
        for (int kk = 0; kk < 2; ++kk)
#pragma unroll
            for (int ni = 0; ni < 4; ++ni)
                bfv[kk][ni] = *(const bf16x8*)(const void*)(gB[ni] + kk * 32);
#pragma unroll
        for (int ni = 0; ni < 4; ++ni) gB[ni] += 64;

        __syncthreads();

#pragma unroll
        for (int kk = 0; kk < 2; ++kk) {
            const int pch = ((kk << 2) + fq) ^ fx;   // physical 16B chunk 0..7
            const int off = pch * 8;
            bf16x8 af[4];
#pragma unroll
            for (int mi = 0; mi < 4; ++mi)
                af[mi] = *(const bf16x8*)(const void*)(aRd + off + mi * 1024);
#pragma unroll
            for (int mi = 0; mi < 4; ++mi)
#pragma unroll
                for (int ni = 0; ni < 4; ++ni)
                    acc[mi][ni] = __builtin_amdgcn_mfma_f32_16x16x32_bf16(
                        af[mi], bfv[kk][ni], acc[mi][ni], 0, 0, 0);
        }
        __syncthreads();
    }

    // Epilogue: C/D layout col = lane&15, row = (lane>>4)*4 + reg
#pragma unroll
    for (int ni = 0; ni < 4; ++ni) {
        const int col = bn + (wc << 6) + (ni << 4) + fr;
        const float bv = bias[col];
#pragma unroll
        for (int mi = 0; mi < 4; ++mi) {
            const int r0 = bm + (wr << 6) + (mi << 4) + (fq << 2);
#pragma unroll
            for (int i = 0; i < 4; ++i)
                C[(size_t)(r0 + i) * K_DIM + col] = acc[mi][ni][i] + bv;
        }
    }
}

// ---------------------------------------------------------------------------
extern "C" void kernel_launch(void* const* d_in, const int* in_sizes, int n_in,
                              void* d_out, int out_size, void* d_ws, size_t ws_size,
                              hipStream_t stream)
{
    (void)in_sizes; (void)n_in; (void)out_size; (void)ws_size;

    const float* x    = (const float*)d_in[0];
    KronPtrs P;
    for (int i = 0; i < 8; ++i) {
        P.a[i] = (const float*)d_in[1 + i];
        P.b[i] = (const float*)d_in[9 + i];
    }
    const float* bias = (const float*)d_in[17];

    __hip_bfloat16* Wb = (__hip_bfloat16*)d_ws;                               // 32 MiB
    __hip_bfloat16* Xb = (__hip_bfloat16*)((char*)d_ws +
                          (size_t)K_DIM * K_DIM * sizeof(__hip_bfloat16));    // 32 MiB
    float* y = (float*)d_out;

    prologue_kernel<<<12288, 256, 0, stream>>>(P, x, Wb, Xb);

    dim3 grid(32, 32);
    gemm_kernel<<<grid, 256, 0, stream>>>(Wb, Xb, bias, y);
}